// Round 5
// baseline (11053.773 us; speedup 1.0000x reference)
//
#include <hip/hip_runtime.h>
#include <math.h>

// LSTMPredictor: B=2048 rows, 3x LSTMCell(H=50), P=17, T=512 + 32 future steps.
// fp32 buffers (runtime-sniffed, bf16 fallback kept). One block per CU owns M=8
// batch rows for the whole 544-step recurrence. Weights in per-thread registers:
// thread = (g4 in [0,50), q in [0,8)); g4 owns gates {g4,50+g4,100+g4,150+g4}.
// amdgpu_waves_per_eu(2,2) pins the allocator budget to 256 VGPRs — rounds 3/4
// proved __launch_bounds__ alone leaves the occupancy heuristic at 4 waves/EU
// (128-VGPR cap) and spills the weight arrays to scratch (FETCH 3.4 GB!).
// Gate-phase math is float2 v_pk_fma_f32 (2 FMA/instr). h-state in LDS;
// c-state in registers of the (m,j) update thread.

#define BATCH    2048
#define PP       17
#define HH       50
#define GG       200      // 4*H
#define MROWS    8
#define NTHREADS 512
#define NBLOCKS  (BATCH / MROWS)   // 256
#define KQ1      9        // cell1 K=68 -> 8 slices of 9 (pad to 72, zero weights)
#define KQ2      13       // cell2 K=100 -> 8 x 13 (pad 104)
#define KQ3      13
#define SROWS    171      // 0..16 x | 17..66 h1 | 67..116 h2 | 117..166 h3 | pad
#define GBP      51       // gb4 row pad (50 -> 51 float4) to break bank aliasing

typedef float f2 __attribute__((ext_vector_type(2)));

__device__ __forceinline__ f2 pkfma(float w, f2 s, f2 c) {
#if __has_builtin(__builtin_elementwise_fma)
    f2 wv; wv.x = w; wv.y = w;
    return __builtin_elementwise_fma(wv, s, c);
#else
    f2 r; r.x = fmaf(w, s.x, c.x); r.y = fmaf(w, s.y, c.y); return r;
#endif
}

__device__ __forceinline__ float bf2f(unsigned short u) {
    unsigned int i = ((unsigned int)u) << 16;
    float f; __builtin_memcpy(&f, &i, 4); return f;
}
__device__ __forceinline__ unsigned short f2bf(float f) {
    unsigned int i; __builtin_memcpy(&i, &f, 4);
    return (unsigned short)((i + 0x7fffu + ((i >> 16) & 1u)) >> 16);
}
__device__ __forceinline__ float ldin(const void* p, long i, bool f32) {
    return f32 ? ((const float*)p)[i] : bf2f(((const unsigned short*)p)[i]);
}
// saturation-safe fast sigmoid/tanh (v_exp_f32 + v_rcp_f32)
__device__ __forceinline__ float fsig(float x) {
    float t = exp2f(-1.44269504089f * x);
    return __builtin_amdgcn_rcpf(1.0f + t);
}
__device__ __forceinline__ float ftanh(float x) {
    float t = exp2f(2.88539008178f * x);
    return 1.0f - 2.0f * __builtin_amdgcn_rcpf(t + 1.0f);
}

// ---- dtype sniffer: bf16 weights decode to |v|<=0.142; fp32-as-bf16 gives junk ----
extern "C" __global__ void sniff_dtype(const unsigned short* __restrict__ w,
                                       int* __restrict__ flag) {
    int lane = threadIdx.x;
    bool bad = false;
#pragma unroll
    for (int t = 0; t < 4; ++t) {
        float v = bf2f(w[lane * 4 + t]);
        bad |= !(fabsf(v) <= 1.0f);
    }
    unsigned long long m = __ballot(bad);
    if (lane == 0) flag[0] = (m != 0ULL) ? 1 : 0;   // 1 => fp32 buffers
}

// gate phase: thread (g4,q) accumulates its K-slice of gates {g4,50+g4,100+g4,150+g4}
// for all 8 rows (4 row-pairs, v_pk_fma_f32). State reads wave-uniform (broadcast).
template <int TQ>
__device__ __forceinline__ void gate_phase(const float* __restrict__ S,
                                           float4* __restrict__ gb4,
                                           const float (&w)[4][TQ],
                                           int srow, int g4, int q, bool act) {
    if (!act) return;
    f2 a[4][4];                       // [gate][row-pair]
#pragma unroll
    for (int e = 0; e < 4; ++e)
#pragma unroll
        for (int p = 0; p < 4; ++p) { a[e][p].x = 0.0f; a[e][p].y = 0.0f; }
    const float4* Sp = (const float4*)(S + (srow + q * TQ) * MROWS);
#pragma unroll
    for (int t = 0; t < TQ; ++t) {
        float4 lo = Sp[2 * t];        // wave-uniform -> broadcast
        float4 hi = Sp[2 * t + 1];
        f2 s0, s1, s2, s3;
        s0.x = lo.x; s0.y = lo.y;  s1.x = lo.z; s1.y = lo.w;
        s2.x = hi.x; s2.y = hi.y;  s3.x = hi.z; s3.y = hi.w;
#pragma unroll
        for (int e = 0; e < 4; ++e) {
            float wv = w[e][t];
            a[e][0] = pkfma(wv, s0, a[e][0]);
            a[e][1] = pkfma(wv, s1, a[e][1]);
            a[e][2] = pkfma(wv, s2, a[e][2]);
            a[e][3] = pkfma(wv, s3, a[e][3]);
        }
    }
#pragma unroll
    for (int m = 0; m < 8; ++m) {     // contiguous b128 stores (lanes consecutive)
        float4 v;
        v.x = (m & 1) ? a[0][m >> 1].y : a[0][m >> 1].x;
        v.y = (m & 1) ? a[1][m >> 1].y : a[1][m >> 1].x;
        v.z = (m & 1) ? a[2][m >> 1].y : a[2][m >> 1].x;
        v.w = (m & 1) ? a[3][m >> 1].y : a[3][m >> 1].x;
        gb4[(q * MROWS + m) * GBP + g4] = v;
    }
}

__device__ __forceinline__ void lstm_update(float* __restrict__ S,
                                            const float4* __restrict__ gb4,
                                            const float4* __restrict__ bsv,
                                            float& c, int hrow, int tid) {
    // caller guards tid < 400;  m = tid&7 (conflict-free h write), j = tid>>3
    int m = tid & 7;
    int j = tid >> 3;
    float4 s = bsv[j];                // (i,f,g,o) combined bias
#pragma unroll
    for (int q = 0; q < 8; ++q) {
        float4 v = gb4[(q * MROWS + m) * GBP + j];
        s.x += v.x; s.y += v.y; s.z += v.z; s.w += v.w;
    }
    float cn = fsig(s.y) * c + fsig(s.x) * ftanh(s.z);
    c = cn;
    S[(hrow + j) * MROWS + m] = fsig(s.w) * ftanh(cn);
}

extern "C" __global__ void
__attribute__((amdgpu_flat_work_group_size(NTHREADS, NTHREADS),
               amdgpu_waves_per_eu(2, 2)))
lstm_persistent(const void* __restrict__ x,
                const void* __restrict__ wih1, const void* __restrict__ whh1,
                const void* __restrict__ bih1, const void* __restrict__ bhh1,
                const void* __restrict__ wih2, const void* __restrict__ whh2,
                const void* __restrict__ bih2, const void* __restrict__ bhh2,
                const void* __restrict__ wih3, const void* __restrict__ whh3,
                const void* __restrict__ bih3, const void* __restrict__ bhh3,
                const void* __restrict__ wlin, const void* __restrict__ blin,
                void* __restrict__ out, const int* __restrict__ flag,
                int T, int steps)
{
    const int tid = threadIdx.x;
    __shared__ float  S[SROWS * MROWS];        // 5.5 KB
    __shared__ float4 gb4[8 * MROWS * GBP];    // 52.2 KB  [q][m][j(+pad)] -> (i,f,g,o)
    __shared__ float4 bsv[3][HH];              // 2.4 KB
    __shared__ float  WLt[PP][52];             // 3.5 KB   [p][k], k 50,51 zero
    __shared__ float  bl[PP];

    const bool f32 = (flag[0] != 0);

    const int lane = tid & 63;
    const int q    = tid >> 6;                 // wave-uniform K-slice
    const int g4   = lane;                     // hidden idx; active if < 50
    const bool act = (lane < HH);

    // ---- per-thread register weights (fp32, full precision) ----
    float w1[4][KQ1], w2[4][KQ2], w3[4][KQ3];
    if (act) {
#pragma unroll
        for (int e = 0; e < 4; ++e) {
            const int g = e * HH + g4;
#pragma unroll
            for (int t = 0; t < KQ1; ++t) {
                int k = q * KQ1 + t;
                w1[e][t] = (k < 17) ? ldin(wih1, (long)g * 17 + k, f32)
                         : (k < 67) ? ldin(whh1, (long)g * 50 + (k - 17), f32)
                                    : 0.0f;
            }
#pragma unroll
            for (int t = 0; t < KQ2; ++t) {
                int k = q * KQ2 + t;
                w2[e][t] = (k < 50)  ? ldin(wih2, (long)g * 50 + k, f32)
                         : (k < 100) ? ldin(whh2, (long)g * 50 + (k - 50), f32)
                                     : 0.0f;
            }
#pragma unroll
            for (int t = 0; t < KQ3; ++t) {
                int k = q * KQ3 + t;
                w3[e][t] = (k < 50)  ? ldin(wih3, (long)g * 50 + k, f32)
                         : (k < 100) ? ldin(whh3, (long)g * 50 + (k - 50), f32)
                                     : 0.0f;
            }
        }
    }

    // ---- stage biases (i,f,g,o float4), W_lin^T, zero h+pad, preload x(0) ----
    if (tid < 150) {
        int cc = tid / HH, j = tid - cc * HH;
        const void* bi = (cc == 0) ? bih1 : (cc == 1) ? bih2 : bih3;
        const void* bh = (cc == 0) ? bhh1 : (cc == 1) ? bhh2 : bhh3;
        float4 v;
        v.x = ldin(bi, j,       f32) + ldin(bh, j,       f32);
        v.y = ldin(bi, 50 + j,  f32) + ldin(bh, 50 + j,  f32);
        v.z = ldin(bi, 100 + j, f32) + ldin(bh, 100 + j, f32);
        v.w = ldin(bi, 150 + j, f32) + ldin(bh, 150 + j, f32);
        bsv[cc][j] = v;
    } else if (tid < 150 + PP) {
        bl[tid - 150] = ldin(blin, tid - 150, f32);
    }
    for (int i = tid; i < PP * 52; i += NTHREADS) {
        int p = i / 52, k = i - p * 52;
        WLt[p][k] = (k < 50) ? ldin(wlin, (long)p * 50 + k, f32) : 0.0f;
    }
    for (int i = tid; i < SROWS * MROWS - 136; i += NTHREADS) S[136 + i] = 0.0f;

    const long rowBase = (long)blockIdx.x * MROWS;
    const long xStride = (long)T * PP;
    if (tid < 136) {
        int m = tid / PP, p = tid - (tid / PP) * PP;
        S[p * MROWS + m] = ldin(x, (rowBase + m) * xStride + p, f32);
    }
    float c1 = 0.0f, c2 = 0.0f, c3 = 0.0f;
    __syncthreads();

    const long outStride = (long)steps * PP;
    for (int s = 0; s < steps; ++s) {
        // early-issue next-step x loads from gate-idle lanes (latency hidden
        // behind all 6 gate/update phases; committed to LDS in phase 7)
        float xp0 = 0.0f, xp1 = 0.0f;
        int u0 = 136, u1 = 136;
        if (lane >= HH && s + 1 < T) {
            int idx = q * 14 + (lane - HH);          // 0..111
            u0 = idx; u1 = idx + 112;
            if (u0 < 136)
                xp0 = ldin(x, (rowBase + u0 / PP) * xStride + (long)(s + 1) * PP + (u0 % PP), f32);
            if (u1 < 136)
                xp1 = ldin(x, (rowBase + u1 / PP) * xStride + (long)(s + 1) * PP + (u1 % PP), f32);
        }

        gate_phase<KQ1>(S, gb4, w1, 0, g4, q, act);            // cell1: [x|h1]
        __syncthreads();
        if (tid < 400) lstm_update(S, gb4, bsv[0], c1, 17, tid);
        __syncthreads();
        gate_phase<KQ2>(S, gb4, w2, 17, g4, q, act);           // cell2: [h1|h2]
        __syncthreads();
        if (tid < 400) lstm_update(S, gb4, bsv[1], c2, 67, tid);
        __syncthreads();
        gate_phase<KQ3>(S, gb4, w3, 67, g4, q, act);           // cell3: [h2|h3]
        __syncthreads();
        if (tid < 400) lstm_update(S, gb4, bsv[2], c3, 117, tid);
        __syncthreads();
        // ---- linear head + output + next input (feedback or prefetched x) ----
        if (tid < 136) {
            int m = tid / PP, p = tid - (tid / PP) * PP;
            float acc = bl[p];
            const float4* wp = (const float4*)(&WLt[p][0]);
#pragma unroll
            for (int kk = 0; kk < 13; ++kk) {       // k 50..51: zero W x zero S pad
                float4 wv = wp[kk];
                int k = 4 * kk;
                acc = fmaf(wv.x, S[(117 + k) * MROWS + m], acc);
                acc = fmaf(wv.y, S[(118 + k) * MROWS + m], acc);
                acc = fmaf(wv.z, S[(119 + k) * MROWS + m], acc);
                acc = fmaf(wv.w, S[(120 + k) * MROWS + m], acc);
            }
            long oi = (rowBase + m) * outStride + (long)s * PP + p;
            if (f32) ((float*)out)[oi] = acc;
            else     ((unsigned short*)out)[oi] = f2bf(acc);
            if (s + 1 >= T && s + 1 < steps)        // autoregressive feedback
                S[p * MROWS + m] = acc;
        }
        if (lane >= HH && s + 1 < T) {              // commit prefetched x
            if (u0 < 136) S[(u0 % PP) * MROWS + (u0 / PP)] = xp0;
            if (u1 < 136) S[(u1 % PP) * MROWS + (u1 / PP)] = xp1;
        }
        __syncthreads();
    }
}

extern "C" void kernel_launch(void* const* d_in, const int* in_sizes, int n_in,
                              void* d_out, int out_size, void* d_ws, size_t ws_size,
                              hipStream_t stream) {
    (void)ws_size; (void)n_in;
    int* flag = (int*)d_ws;

    const int T     = in_sizes[0] / (BATCH * PP);   // 512
    const int steps = out_size / (BATCH * PP);      // 544

    sniff_dtype<<<1, 64, 0, stream>>>((const unsigned short*)d_in[1], flag);

    lstm_persistent<<<NBLOCKS, NTHREADS, 0, stream>>>(
        d_in[0],
        d_in[1], d_in[2], d_in[3], d_in[4],
        d_in[5], d_in[6], d_in[7], d_in[8],
        d_in[9], d_in[10], d_in[11], d_in[12],
        d_in[13], d_in[14],
        d_out, flag, T, steps);
}

// Round 6
// 8220.669 us; speedup vs baseline: 1.3446x; 1.3446x over previous
//
#include <hip/hip_runtime.h>
#include <math.h>

// LSTMPredictor: B=2048 rows, 3x LSTMCell(H=50), P=17, T=512 + 32 future steps.
// fp32 buffers (runtime-sniffed, bf16 fallback kept). One block per CU owns M=8
// batch rows for the whole 544-step recurrence.
//
// REGISTER BUDGET IS THE LAW (rounds 3-5): allocator caps at 128 VGPRs no matter
// what attributes we pass; anything over spills to scratch and FETCH_SIZE explodes
// (3.4 GB r4, 16.4 GB r5). This version fits by construction:
//   1024 threads = 16 waves = q-slice[0,8) x gate-half{0,1}; lane j in [0,50).
//   Thread owns 2 gates: gh=0 -> (i_j, g_j), gh=1 -> (f_j, o_j).
//   Weights/thread = 2*(9+13+13) = 70 fp32 + 16 acc -> ~116 VGPRs.
// State reads wave-uniform (LDS broadcast); partials as float2 {A,B} in padded
// gb (stride 51 f2) so update reads are ~2-way max; h-writes conflict-free.

#define BATCH    2048
#define PP       17
#define HH       50
#define MROWS    8
#define NTHREADS 1024
#define NBLOCKS  (BATCH / MROWS)   // 256
#define KQ1      9        // cell1 K=68 -> 8 slices of 9 (zero-padded weights)
#define KQ2      13       // cell2/3 K=100 -> 8 x 13 (zero-padded weights)
#define KQ3      13
#define SROWS    171      // 0..16 x | 17..66 h1 | 67..116 h2 | 117..166 h3 | 167..170 pad(0)
#define JP       51       // gb row pad (50 -> 51 float2) to stagger update-read banks

typedef float f2 __attribute__((ext_vector_type(2)));

__device__ __forceinline__ f2 pkfma(float w, f2 s, f2 c) {
#if __has_builtin(__builtin_elementwise_fma)
    f2 wv; wv.x = w; wv.y = w;
    return __builtin_elementwise_fma(wv, s, c);
#else
    f2 r; r.x = fmaf(w, s.x, c.x); r.y = fmaf(w, s.y, c.y); return r;
#endif
}

__device__ __forceinline__ float bf2f(unsigned short u) {
    unsigned int i = ((unsigned int)u) << 16;
    float f; __builtin_memcpy(&f, &i, 4); return f;
}
__device__ __forceinline__ unsigned short f2bf(float f) {
    unsigned int i; __builtin_memcpy(&i, &f, 4);
    return (unsigned short)((i + 0x7fffu + ((i >> 16) & 1u)) >> 16);
}
__device__ __forceinline__ float ldin(const void* p, long i, bool f32) {
    return f32 ? ((const float*)p)[i] : bf2f(((const unsigned short*)p)[i]);
}
// saturation-safe fast sigmoid/tanh (v_exp_f32 + v_rcp_f32)
__device__ __forceinline__ float fsig(float x) {
    float t = exp2f(-1.44269504089f * x);
    return __builtin_amdgcn_rcpf(1.0f + t);
}
__device__ __forceinline__ float ftanh(float x) {
    float t = exp2f(2.88539008178f * x);
    return 1.0f - 2.0f * __builtin_amdgcn_rcpf(t + 1.0f);
}

// ---- dtype sniffer: bf16 weights decode to |v|<=0.142; fp32-as-bf16 gives junk ----
extern "C" __global__ void sniff_dtype(const unsigned short* __restrict__ w,
                                       int* __restrict__ flag) {
    int lane = threadIdx.x;
    bool bad = false;
#pragma unroll
    for (int t = 0; t < 4; ++t) {
        float v = bf2f(w[lane * 4 + t]);
        bad |= !(fabsf(v) <= 1.0f);
    }
    unsigned long long m = __ballot(bad);
    if (lane == 0) flag[0] = (m != 0ULL) ? 1 : 0;   // 1 => fp32 buffers
}

#define GQM(gh, q, m) ((((gh) * 8 + (q)) * MROWS + (m)) * JP)

// gate phase: thread (j,gh,q) accumulates its K-slice of its 2 gates for all 8
// rows (v_pk_fma_f32). State reads wave-uniform (LDS broadcast); b64 partial
// stores at consecutive-lane addresses (conflict-free).
template <int TQ>
__device__ __forceinline__ void gate_phase(const float* __restrict__ S,
                                           f2* __restrict__ gb,
                                           const float (&w)[2][TQ],
                                           int srow, int j, int q, int gh, bool act) {
    if (!act) return;
    f2 aA[4], aB[4];                  // 2 gates x 4 row-pairs
#pragma unroll
    for (int p = 0; p < 4; ++p) { aA[p].x = 0.f; aA[p].y = 0.f; aB[p].x = 0.f; aB[p].y = 0.f; }
    const float4* Sp = (const float4*)(S + (srow + q * TQ) * MROWS);
#pragma unroll
    for (int t = 0; t < TQ; ++t) {
        float4 lo = Sp[2 * t];        // wave-uniform -> broadcast
        float4 hi = Sp[2 * t + 1];
        f2 s0, s1, s2, s3;
        s0.x = lo.x; s0.y = lo.y;  s1.x = lo.z; s1.y = lo.w;
        s2.x = hi.x; s2.y = hi.y;  s3.x = hi.z; s3.y = hi.w;
        float wa = w[0][t], wb = w[1][t];
        aA[0] = pkfma(wa, s0, aA[0]); aA[1] = pkfma(wa, s1, aA[1]);
        aA[2] = pkfma(wa, s2, aA[2]); aA[3] = pkfma(wa, s3, aA[3]);
        aB[0] = pkfma(wb, s0, aB[0]); aB[1] = pkfma(wb, s1, aB[1]);
        aB[2] = pkfma(wb, s2, aB[2]); aB[3] = pkfma(wb, s3, aB[3]);
    }
    f2* go = gb + GQM(gh, q, 0) + j;
#pragma unroll
    for (int m = 0; m < 8; ++m) {     // b64 stores, lanes consecutive -> conflict-free
        f2 v;
        v.x = (m & 1) ? aA[m >> 1].y : aA[m >> 1].x;
        v.y = (m & 1) ? aB[m >> 1].y : aB[m >> 1].x;
        go[m * JP] = v;
    }
}

__device__ __forceinline__ void lstm_update(float* __restrict__ S,
                                            const f2* __restrict__ gb,
                                            const float4* __restrict__ bsv,
                                            float& c, int hrow, int tid) {
    // caller guards tid < 400;  m = tid&7 (conflict-free h write), j = tid>>3
    int m = tid & 7;
    int j = tid >> 3;
    float4 s = bsv[j];                // (i,f,g,o) combined bias
#pragma unroll
    for (int q = 0; q < 8; ++q) {
        f2 v0 = gb[GQM(0, q, m) + j];   // {i_part, g_part}
        f2 v1 = gb[GQM(1, q, m) + j];   // {f_part, o_part}
        s.x += v0.x; s.z += v0.y;
        s.y += v1.x; s.w += v1.y;
    }
    float cn = fsig(s.y) * c + fsig(s.x) * ftanh(s.z);
    c = cn;
    S[(hrow + j) * MROWS + m] = fsig(s.w) * ftanh(cn);
}

extern "C" __global__ void
__attribute__((amdgpu_flat_work_group_size(NTHREADS, NTHREADS)))
lstm_persistent(const void* __restrict__ x,
                const void* __restrict__ wih1, const void* __restrict__ whh1,
                const void* __restrict__ bih1, const void* __restrict__ bhh1,
                const void* __restrict__ wih2, const void* __restrict__ whh2,
                const void* __restrict__ bih2, const void* __restrict__ bhh2,
                const void* __restrict__ wih3, const void* __restrict__ whh3,
                const void* __restrict__ bih3, const void* __restrict__ bhh3,
                const void* __restrict__ wlin, const void* __restrict__ blin,
                void* __restrict__ out, const int* __restrict__ flag,
                int T, int steps)
{
    const int tid = threadIdx.x;
    __shared__ float  S[SROWS * MROWS];        // 5.5 KB
    __shared__ f2     gb[2 * 8 * MROWS * JP];  // 52.2 KB  [gh][q][m][j(+pad)]
    __shared__ float4 bsv[3][HH];              // 2.4 KB   (i,f,g,o) combined bias
    __shared__ float  WLt[PP][52];             // 3.5 KB   [p][k], k 50,51 zero
    __shared__ float  bl[PP];

    const bool f32 = (flag[0] != 0);

    const int lane = tid & 63;
    const int wv   = tid >> 6;                 // 0..15
    const int q    = wv >> 1;                  // wave-uniform K-slice 0..7
    const int gh   = wv & 1;                   // gate-half: 0 -> (i,g), 1 -> (f,o)
    const int j    = lane;                     // hidden idx; active if < 50
    const bool act = (lane < HH);

    // gate ids this thread owns
    const int gA = gh * HH + j;                // i_j (gh=0) or f_j (gh=1)
    const int gB = 2 * HH + gh * HH + j;       // g_j (gh=0) or o_j (gh=1)

    // ---- per-thread register weights (fp32, full precision): 70 floats ----
    float w1[2][KQ1], w2[2][KQ2], w3[2][KQ3];
    if (act) {
#pragma unroll
        for (int e = 0; e < 2; ++e) {
            const int g = e ? gB : gA;
#pragma unroll
            for (int t = 0; t < KQ1; ++t) {
                int k = q * KQ1 + t;
                w1[e][t] = (k < 17) ? ldin(wih1, (long)g * 17 + k, f32)
                         : (k < 67) ? ldin(whh1, (long)g * 50 + (k - 17), f32)
                                    : 0.0f;
            }
#pragma unroll
            for (int t = 0; t < KQ2; ++t) {
                int k = q * KQ2 + t;
                w2[e][t] = (k < 50)  ? ldin(wih2, (long)g * 50 + k, f32)
                         : (k < 100) ? ldin(whh2, (long)g * 50 + (k - 50), f32)
                                     : 0.0f;
            }
#pragma unroll
            for (int t = 0; t < KQ3; ++t) {
                int k = q * KQ3 + t;
                w3[e][t] = (k < 50)  ? ldin(wih3, (long)g * 50 + k, f32)
                         : (k < 100) ? ldin(whh3, (long)g * 50 + (k - 50), f32)
                                     : 0.0f;
            }
        }
    }

    // ---- stage biases (i,f,g,o float4), W_lin^T, zero h+pad, preload x(0) ----
    if (tid < 150) {
        int cc = tid / HH, jj = tid - cc * HH;
        const void* bi = (cc == 0) ? bih1 : (cc == 1) ? bih2 : bih3;
        const void* bh = (cc == 0) ? bhh1 : (cc == 1) ? bhh2 : bhh3;
        float4 v;
        v.x = ldin(bi, jj,       f32) + ldin(bh, jj,       f32);
        v.y = ldin(bi, 50 + jj,  f32) + ldin(bh, 50 + jj,  f32);
        v.z = ldin(bi, 100 + jj, f32) + ldin(bh, 100 + jj, f32);
        v.w = ldin(bi, 150 + jj, f32) + ldin(bh, 150 + jj, f32);
        bsv[cc][jj] = v;
    } else if (tid < 150 + PP) {
        bl[tid - 150] = ldin(blin, tid - 150, f32);
    }
    for (int i = tid; i < PP * 52; i += NTHREADS) {
        int p = i / 52, k = i - p * 52;
        WLt[p][k] = (k < 50) ? ldin(wlin, (long)p * 50 + k, f32) : 0.0f;
    }
    for (int i = tid; i < SROWS * MROWS - 136; i += NTHREADS) S[136 + i] = 0.0f;

    const long rowBase = (long)blockIdx.x * MROWS;
    const long xStride = (long)T * PP;
    if (tid < 136) {
        int m = tid / PP, p = tid - (tid / PP) * PP;
        S[p * MROWS + m] = ldin(x, (rowBase + m) * xStride + p, f32);
    }
    float c1 = 0.0f, c2 = 0.0f, c3 = 0.0f;
    __syncthreads();

    const long outStride = (long)steps * PP;
    for (int s = 0; s < steps; ++s) {
        // early-issue next-step x loads from gate-idle lanes (latency hidden
        // behind all 6 gate/update phases; committed to LDS in phase 7)
        float xp = 0.0f;
        int u = 136;
        if (lane >= HH && s + 1 < T) {
            int idx = wv * 14 + (lane - HH);         // 0..223, unique
            if (idx < 136) {
                u = idx;
                xp = ldin(x, (rowBase + u / PP) * xStride + (long)(s + 1) * PP + (u % PP), f32);
            }
        }

        gate_phase<KQ1>(S, gb, w1, 0, j, q, gh, act);           // cell1: [x|h1]
        __syncthreads();
        if (tid < 400) lstm_update(S, gb, bsv[0], c1, 17, tid);
        __syncthreads();
        gate_phase<KQ2>(S, gb, w2, 17, j, q, gh, act);          // cell2: [h1|h2]
        __syncthreads();
        if (tid < 400) lstm_update(S, gb, bsv[1], c2, 67, tid);
        __syncthreads();
        gate_phase<KQ3>(S, gb, w3, 67, j, q, gh, act);          // cell3: [h2|h3]
        __syncthreads();
        if (tid < 400) lstm_update(S, gb, bsv[2], c3, 117, tid);
        __syncthreads();
        // ---- linear head + output + next input (feedback or prefetched x) ----
        if (tid < 136) {
            int m = tid / PP, p = tid - (tid / PP) * PP;
            float acc = bl[p];
            const float4* wp = (const float4*)(&WLt[p][0]);
#pragma unroll
            for (int kk = 0; kk < 13; ++kk) {        // k 50..51: zero W x zero S pad
                float4 wv4 = wp[kk];
                int k = 4 * kk;
                acc = fmaf(wv4.x, S[(117 + k) * MROWS + m], acc);
                acc = fmaf(wv4.y, S[(118 + k) * MROWS + m], acc);
                acc = fmaf(wv4.z, S[(119 + k) * MROWS + m], acc);
                acc = fmaf(wv4.w, S[(120 + k) * MROWS + m], acc);
            }
            long oi = (rowBase + m) * outStride + (long)s * PP + p;
            if (f32) ((float*)out)[oi] = acc;
            else     ((unsigned short*)out)[oi] = f2bf(acc);
            if (s + 1 >= T && s + 1 < steps)         // autoregressive feedback
                S[p * MROWS + m] = acc;
        }
        if (u < 136)                                 // commit prefetched x
            S[(u % PP) * MROWS + (u / PP)] = xp;
        __syncthreads();
    }
}

extern "C" void kernel_launch(void* const* d_in, const int* in_sizes, int n_in,
                              void* d_out, int out_size, void* d_ws, size_t ws_size,
                              hipStream_t stream) {
    (void)ws_size; (void)n_in;
    int* flag = (int*)d_ws;

    const int T     = in_sizes[0] / (BATCH * PP);   // 512
    const int steps = out_size / (BATCH * PP);      // 544

    sniff_dtype<<<1, 64, 0, stream>>>((const unsigned short*)d_in[1], flag);

    lstm_persistent<<<NBLOCKS, NTHREADS, 0, stream>>>(
        d_in[0],
        d_in[1], d_in[2], d_in[3], d_in[4],
        d_in[5], d_in[6], d_in[7], d_in[8],
        d_in[9], d_in[10], d_in[11], d_in[12],
        d_in[13], d_in[14],
        d_out, flag, T, steps);
}

// Round 7
// 5272.719 us; speedup vs baseline: 2.0964x; 1.5591x over previous
//
#include <hip/hip_runtime.h>
#include <math.h>

// LSTMPredictor: B=2048 rows, 3x LSTMCell(H=50), P=17, T=512 + 32 future steps.
// fp32 buffers (runtime-sniffed, bf16 fallback kept). One block per CU owns M=8
// rows for all 544 steps.
//
// ALLOCATOR LAW (rounds 3-6): VGPR cap is fixed by block shape — 512 thr -> 128,
// 1024 thr -> 64 — regardless of launch_bounds / waves_per_eu. Private scratch
// spill is catastrophic (per-thread working set >> L2 -> 3-19 GB HBM FETCH).
// So: fit 128 by construction. thread = (gate g in [0,200) within 256-lane
// group, K-half kh in {0,1}). Registers hold fp32 weights for cells 1+2 only
// (34+50 = 84); cell-3 weights STREAM from a transposed fp32 copy W3T[k][g] in
// d_ws (coalesced lane-consecutive loads; 80 KB shared per XCD -> L1/L2 hits).
// Deliberate remat instead of accidental spill. Partials: row-pair f2, b64
// conflict-free stores, <=2-way reads (free). ~117 VGPR demand.

#define BATCH    2048
#define PP       17
#define HH       50
#define GP       200      // gate dimension (4*H)
#define MROWS    8
#define NTHREADS 512
#define NBLOCKS  (BATCH / MROWS)   // 256
#define SROWS    171      // 0..16 x | 17..66 h1 | 67..116 h2 | 117..166 h3 | 167..170 pad(0)
#define WS_W3T_OFF 256    // fp32 W3T[100][200] at d_ws + 256 (80 KB)

typedef float f2 __attribute__((ext_vector_type(2)));

__device__ __forceinline__ f2 pkfma(float w, f2 s, f2 c) {
#if __has_builtin(__builtin_elementwise_fma)
    f2 wv; wv.x = w; wv.y = w;
    return __builtin_elementwise_fma(wv, s, c);
#else
    f2 r; r.x = fmaf(w, s.x, c.x); r.y = fmaf(w, s.y, c.y); return r;
#endif
}

__device__ __forceinline__ float bf2f(unsigned short u) {
    unsigned int i = ((unsigned int)u) << 16;
    float f; __builtin_memcpy(&f, &i, 4); return f;
}
__device__ __forceinline__ unsigned short f2bf(float f) {
    unsigned int i; __builtin_memcpy(&i, &f, 4);
    return (unsigned short)((i + 0x7fffu + ((i >> 16) & 1u)) >> 16);
}
__device__ __forceinline__ float ldin(const void* p, long i, bool f32) {
    return f32 ? ((const float*)p)[i] : bf2f(((const unsigned short*)p)[i]);
}
// saturation-safe fast sigmoid/tanh (v_exp_f32 + v_rcp_f32)
__device__ __forceinline__ float fsig(float x) {
    float t = exp2f(-1.44269504089f * x);
    return __builtin_amdgcn_rcpf(1.0f + t);
}
__device__ __forceinline__ float ftanh(float x) {
    float t = exp2f(2.88539008178f * x);
    return 1.0f - 2.0f * __builtin_amdgcn_rcpf(t + 1.0f);
}

// ---- dtype sniffer: bf16 weights decode to |v|<=0.142; fp32-as-bf16 gives junk ----
extern "C" __global__ void sniff_dtype(const unsigned short* __restrict__ w,
                                       int* __restrict__ flag) {
    int lane = threadIdx.x;
    bool bad = false;
#pragma unroll
    for (int t = 0; t < 4; ++t) {
        float v = bf2f(w[lane * 4 + t]);
        bad |= !(fabsf(v) <= 1.0f);
    }
    unsigned long long m = __ballot(bad);
    if (lane == 0) flag[0] = (m != 0ULL) ? 1 : 0;   // 1 => fp32 buffers
}

// ---- prep: W3T[k][g] fp32 transpose of cell-3 weights into workspace ----
extern "C" __global__ void prep_w3t(const void* __restrict__ wih3,
                                    const void* __restrict__ whh3,
                                    float* __restrict__ w3t,
                                    const int* __restrict__ flag) {
    const bool f32 = (flag[0] != 0);
    int i = blockIdx.x * 256 + threadIdx.x;
    if (i < 100 * GP) {
        int k = i / GP, g = i - k * GP;
        w3t[i] = (k < 50) ? ldin(wih3, (long)g * 50 + k, f32)
                          : ldin(whh3, (long)g * 50 + (k - 50), f32);
    }
}

// store row-pair partials: gb2[(kh*4+mp)*GP + g], lanes g consecutive
__device__ __forceinline__ void gate_store(f2* __restrict__ gb2, int kh, int g,
                                           const f2 (&a)[4]) {
    f2* go = gb2 + (kh * 4) * GP + g;
    go[0] = a[0]; go[GP] = a[1]; go[2 * GP] = a[2]; go[3 * GP] = a[3];
}

// register-weight gate phase (cells 1,2): thread (g,kh) does its K-half of gate g
// for all 8 rows. State reads wave-uniform (LDS broadcast), pk-fma math.
template <int TQ>
__device__ __forceinline__ void gate_phase_reg(const float* __restrict__ S,
                                               f2* __restrict__ gb2,
                                               const float (&w)[TQ], float bias,
                                               int srow, int g, int kh, bool act) {
    if (!act) return;
    f2 a[4];
    float b = kh ? 0.0f : bias;
#pragma unroll
    for (int p = 0; p < 4; ++p) { a[p].x = b; a[p].y = b; }
    const float4* Sp = (const float4*)(S + srow * MROWS);
#pragma unroll
    for (int t = 0; t < TQ; ++t) {
        float4 lo = Sp[2 * t];        // wave-uniform -> broadcast
        float4 hi = Sp[2 * t + 1];
        f2 s0, s1, s2, s3;
        s0.x = lo.x; s0.y = lo.y;  s1.x = lo.z; s1.y = lo.w;
        s2.x = hi.x; s2.y = hi.y;  s3.x = hi.z; s3.y = hi.w;
        float wk = w[t];
        a[0] = pkfma(wk, s0, a[0]); a[1] = pkfma(wk, s1, a[1]);
        a[2] = pkfma(wk, s2, a[2]); a[3] = pkfma(wk, s3, a[3]);
    }
    gate_store(gb2, kh, g, a);
}

// streamed-weight gate phase (cell 3): weights from W3T[k][g] (coalesced b32,
// L1/L2-resident 80 KB shared by the XCD) or strided fallback if no workspace.
__device__ __forceinline__ void gate_phase_stream(const float* __restrict__ S,
                                                  f2* __restrict__ gb2,
                                                  const float* __restrict__ w3t,
                                                  const void* __restrict__ wih3,
                                                  const void* __restrict__ whh3,
                                                  bool f32, int g, int kh, bool act) {
    if (!act) return;
    f2 a[4];
#pragma unroll
    for (int p = 0; p < 4; ++p) { a[p].x = 0.0f; a[p].y = 0.0f; }
    const float4* Sp = (const float4*)(S + (67 + kh * 50) * MROWS);
    if (w3t) {
        const float* wp = w3t + (kh * 50) * GP + g;
#pragma unroll 10
        for (int t = 0; t < 50; ++t) {
            float wk = wp[t * GP];            // lanes consecutive -> coalesced
            float4 lo = Sp[2 * t];
            float4 hi = Sp[2 * t + 1];
            f2 s0, s1, s2, s3;
            s0.x = lo.x; s0.y = lo.y;  s1.x = lo.z; s1.y = lo.w;
            s2.x = hi.x; s2.y = hi.y;  s3.x = hi.z; s3.y = hi.w;
            a[0] = pkfma(wk, s0, a[0]); a[1] = pkfma(wk, s1, a[1]);
            a[2] = pkfma(wk, s2, a[2]); a[3] = pkfma(wk, s3, a[3]);
        }
    } else {                                  // fallback: ws too small
        const void* wsrc = kh ? whh3 : wih3;
#pragma unroll 5
        for (int t = 0; t < 50; ++t) {
            float wk = ldin(wsrc, (long)g * 50 + t, f32);
            float4 lo = Sp[2 * t];
            float4 hi = Sp[2 * t + 1];
            f2 s0, s1, s2, s3;
            s0.x = lo.x; s0.y = lo.y;  s1.x = lo.z; s1.y = lo.w;
            s2.x = hi.x; s2.y = hi.y;  s3.x = hi.z; s3.y = hi.w;
            a[0] = pkfma(wk, s0, a[0]); a[1] = pkfma(wk, s1, a[1]);
            a[2] = pkfma(wk, s2, a[2]); a[3] = pkfma(wk, s3, a[3]);
        }
    }
    gate_store(gb2, kh, g, a);
}

__device__ __forceinline__ void lstm_update(float* __restrict__ S,
                                            const float* __restrict__ gbf,
                                            float& c, int hrow, int tid) {
    // caller guards tid < 400; m = tid&7 (h-write addr = hrow*8 + tid), j = tid>>3
    int m = tid & 7;
    int j = tid >> 3;
    int base = (m >> 1) * (2 * GP) + (m & 1);   // float index into gb2 viewed flat
    const float* p0 = gbf + base;               // kh = 0
    const float* p1 = gbf + base + 8 * GP;      // kh = 1
    float ii = p0[2 * j]              + p1[2 * j];
    float ff = p0[2 * (50 + j)]       + p1[2 * (50 + j)];
    float gg = p0[2 * (100 + j)]      + p1[2 * (100 + j)];
    float oo = p0[2 * (150 + j)]      + p1[2 * (150 + j)];
    float cn = fsig(ff) * c + fsig(ii) * ftanh(gg);
    c = cn;
    S[(hrow + j) * MROWS + m] = fsig(oo) * ftanh(cn);
}

extern "C" __global__ void __launch_bounds__(NTHREADS)
lstm_persistent(const void* __restrict__ x,
                const void* __restrict__ wih1, const void* __restrict__ whh1,
                const void* __restrict__ bih1, const void* __restrict__ bhh1,
                const void* __restrict__ wih2, const void* __restrict__ whh2,
                const void* __restrict__ bih2, const void* __restrict__ bhh2,
                const void* __restrict__ wih3, const void* __restrict__ whh3,
                const void* __restrict__ bih3, const void* __restrict__ bhh3,
                const void* __restrict__ wlin, const void* __restrict__ blin,
                void* __restrict__ out, const int* __restrict__ flag,
                const float* __restrict__ w3t, int T, int steps)
{
    const int tid = threadIdx.x;
    __shared__ float S[SROWS * MROWS];       // 5.5 KB
    __shared__ f2    gb2[2 * 4 * GP];        // 12.8 KB  [kh][row-pair][gate]
    __shared__ float bs[3 * GP];             // 2.4 KB   combined biases
    __shared__ float WLt[PP][52];            // 3.5 KB   [p][k], k 50,51 zero
    __shared__ float bl[PP];

    const bool f32 = (flag[0] != 0);

    const int g  = tid & 255;                // gate id; active if < 200
    const int kh = tid >> 8;                 // K-half (wave-uniform)
    const bool act = (g < GP);

    // ---- per-thread register weights: cells 1+2 only (84 fp32) ----
    float w1[34], w2[50];
    if (act) {
        if (kh == 0) {                       // cell1 k = 0..33 (x | h1 cols 0..16)
#pragma unroll
            for (int t = 0; t < 17; ++t)  w1[t] = ldin(wih1, (long)g * 17 + t, f32);
#pragma unroll
            for (int t = 17; t < 34; ++t) w1[t] = ldin(whh1, (long)g * 50 + (t - 17), f32);
        } else {                             // cell1 k = 34..67 (h1 cols 17..49 | pad)
#pragma unroll
            for (int t = 0; t < 33; ++t)  w1[t] = ldin(whh1, (long)g * 50 + 17 + t, f32);
            w1[33] = 0.0f;                   // k=67 pad (multiplies h2[0] row -> must be 0)
        }
#pragma unroll
        for (int t = 0; t < 50; ++t)
            w2[t] = ldin(kh ? whh2 : wih2, (long)g * 50 + t, f32);
    }

    // ---- stage combined biases, W_lin^T, zero h-state+pad, preload x(0) ----
    if (tid < GP) {
        bs[tid]          = ldin(bih1, tid, f32) + ldin(bhh1, tid, f32);
        bs[GP + tid]     = ldin(bih2, tid, f32) + ldin(bhh2, tid, f32);
        bs[2 * GP + tid] = ldin(bih3, tid, f32) + ldin(bhh3, tid, f32);
    } else if (tid < GP + PP) {
        bl[tid - GP] = ldin(blin, tid - GP, f32);
    }
    for (int i = tid; i < PP * 52; i += NTHREADS) {
        int p = i / 52, k = i - p * 52;
        WLt[p][k] = (k < 50) ? ldin(wlin, (long)p * 50 + k, f32) : 0.0f;
    }
    for (int i = tid; i < SROWS * MROWS - 136; i += NTHREADS) S[136 + i] = 0.0f;

    const long rowBase = (long)blockIdx.x * MROWS;
    const long xStride = (long)T * PP;
    if (tid < 136) {
        int m = tid / PP, p = tid - (tid / PP) * PP;
        S[p * MROWS + m] = ldin(x, (rowBase + m) * xStride + p, f32);
    }
    float c1 = 0.0f, c2 = 0.0f, c3 = 0.0f;
    const float bias1 = act ? bs[g] : 0.0f;          // read after staging barrier? no:
    __syncthreads();                                  // bs written above by tid<200 of
    const float b1 = act ? bs[g] : 0.0f;              // this block -> read post-barrier
    const float b2 = act ? bs[GP + g] : 0.0f;
    const float b3 = act ? bs[2 * GP + g] : 0.0f;
    (void)bias1;

    const long outStride = (long)steps * PP;
    for (int s = 0; s < steps; ++s) {
        // early-issue next-step x loads from the mostly-idle waves 3 & 7
        // (g >= 200); committed to LDS at end of step.
        float xp0 = 0.0f, xp1 = 0.0f;
        int u0 = 999, u1 = 999;
        if (g >= GP && s + 1 < T) {
            int idx = kh * 56 + (g - GP);            // 0..111
            u0 = idx; u1 = idx + 112;
            xp0 = ldin(x, (rowBase + u0 / PP) * xStride + (long)(s + 1) * PP + (u0 % PP), f32);
            if (u1 < 136)
                xp1 = ldin(x, (rowBase + u1 / PP) * xStride + (long)(s + 1) * PP + (u1 % PP), f32);
        }

        gate_phase_reg<34>(S, gb2, w1, b1, kh * 34, g, kh, act);        // cell1 [x|h1]
        __syncthreads();
        if (tid < 400) lstm_update(S, (const float*)gb2, c1, 17, tid);
        __syncthreads();
        gate_phase_reg<50>(S, gb2, w2, b2, 17 + kh * 50, g, kh, act);   // cell2 [h1|h2]
        __syncthreads();
        if (tid < 400) lstm_update(S, (const float*)gb2, c2, 67, tid);
        __syncthreads();
        gate_phase_stream(S, gb2, w3t, wih3, whh3, f32, g, kh, act);    // cell3 [h2|h3]
        if (act && kh == 0) {      // cell3 bias: fold into kh=0 partial via LDS add
            // cheaper: add bias to the stored partial of row-pair 0..3
        }
        __syncthreads();
        if (tid < 400) {
            // add cell3 bias at update time (stream phase stored raw partials)
            int m = tid & 7, j = tid >> 3;
            float bb = bs[2 * GP + j];   // per-j biases looked up 4x below instead
            (void)bb; (void)m;
        }
        if (tid < 400) {
            int m = tid & 7;
            int j = tid >> 3;
            int base = (m >> 1) * (2 * GP) + (m & 1);
            const float* gbf = (const float*)gb2;
            const float* p0 = gbf + base;
            const float* p1 = gbf + base + 8 * GP;
            float ii = bs[2 * GP + j]  * 0.0f; // placeholder, real bias below
            ii = p0[2 * j]         + p1[2 * j]         + bs[2 * GP + j];
            float ff = p0[2 * (50 + j)]  + p1[2 * (50 + j)]  + bs[2 * GP + 50 + j] * 0.0f;
            // NOTE: combined bias bs3 covers ALL 4 gates of cell3; indices below
            ff = p0[2 * (50 + j)]  + p1[2 * (50 + j)];
            float gg = p0[2 * (100 + j)] + p1[2 * (100 + j)];
            float oo = p0[2 * (150 + j)] + p1[2 * (150 + j)];
            // bias for f,g,o gates of cell3 lives at bs[2GP + {50,100,150} + j]?
            // bs3 was stored per-gate-id (0..199), so:
            ff += 0.0f; gg += 0.0f; oo += 0.0f;
            float bi = bs[2 * GP + j];          // gate i_j  (id j)
            (void)bi;
            float cn;
            {
                float bI = 0.0f, bF = 0.0f, bG = 0.0f, bO = 0.0f;
                // bs3[gate] holds bih3[gate]+bhh3[gate] for gate in [0,200)
                bI = 0.0f; // already added to ii above
                bF = bs[2 * GP + 50 + j];
                bG = bs[2 * GP + 100 + j];
                bO = bs[2 * GP + 150 + j];
                ff += bF; gg += bG; oo += bO;
                (void)bI;
            }
            cn = fsig(ff) * c3 + fsig(ii) * ftanh(gg);
            c3 = cn;
            S[(117 + j) * MROWS + m] = fsig(oo) * ftanh(cn);
        }
        __syncthreads();
        // ---- linear head + output + next input (feedback or prefetched x) ----
        if (tid < 136) {
            int m = tid / PP, p = tid - (tid / PP) * PP;
            float acc = bl[p];
            const float4* wp = (const float4*)(&WLt[p][0]);
#pragma unroll
            for (int kk = 0; kk < 13; ++kk) {        // k 50..51: zero W x zero S pad
                float4 wv = wp[kk];
                int k = 4 * kk;
                acc = fmaf(wv.x, S[(117 + k) * MROWS + m], acc);
                acc = fmaf(wv.y, S[(118 + k) * MROWS + m], acc);
                acc = fmaf(wv.z, S[(119 + k) * MROWS + m], acc);
                acc = fmaf(wv.w, S[(120 + k) * MROWS + m], acc);
            }
            long oi = (rowBase + m) * outStride + (long)s * PP + p;
            if (f32) ((float*)out)[oi] = acc;
            else     ((unsigned short*)out)[oi] = f2bf(acc);
            if (s + 1 >= T && s + 1 < steps)         // autoregressive feedback
                S[p * MROWS + m] = acc;
        }
        if (g >= GP && s + 1 < T) {                  // commit prefetched x
            S[(u0 % PP) * MROWS + (u0 / PP)] = xp0;
            if (u1 < 136) S[(u1 % PP) * MROWS + (u1 / PP)] = xp1;
        }
        __syncthreads();
    }
}

extern "C" void kernel_launch(void* const* d_in, const int* in_sizes, int n_in,
                              void* d_out, int out_size, void* d_ws, size_t ws_size,
                              hipStream_t stream) {
    (void)n_in;
    int* flag = (int*)d_ws;
    float* w3t = (ws_size >= WS_W3T_OFF + 100 * GP * sizeof(float))
               ? (float*)((char*)d_ws + WS_W3T_OFF) : nullptr;

    const int T     = in_sizes[0] / (BATCH * PP);   // 512
    const int steps = out_size / (BATCH * PP);      // 544

    sniff_dtype<<<1, 64, 0, stream>>>((const unsigned short*)d_in[1], flag);
    if (w3t)
        prep_w3t<<<(100 * GP + 255) / 256, 256, 0, stream>>>(d_in[9], d_in[10], w3t, flag);

    lstm_persistent<<<NBLOCKS, NTHREADS, 0, stream>>>(
        d_in[0],
        d_in[1], d_in[2], d_in[3], d_in[4],
        d_in[5], d_in[6], d_in[7], d_in[8],
        d_in[9], d_in[10], d_in[11], d_in[12],
        d_in[13], d_in[14],
        d_out, flag, w3t, T, steps);
}